// Round 1
// baseline (417.540 us; speedup 1.0000x reference)
//
#include <hip/hip_runtime.h>
#include <stdint.h>

#define DIM   1024
#define HEADS 16
#define DH    64
#define B_    4
#define N_    1024
#define P_    1024
#define J_    2048
#define SCALE_ 8.0f
#define WIND  16

typedef __attribute__((ext_vector_type(8))) short bf16x8;
typedef __attribute__((ext_vector_type(4))) float f32x4;

typedef __attribute__((address_space(1))) void* as1_t;
typedef __attribute__((address_space(3))) void* as3_t;

static __device__ __forceinline__ unsigned short f2bf(float f) {
    union { float f; unsigned u; } v; v.f = f;
    unsigned r = v.u + 0x7fffu + ((v.u >> 16) & 1u);
    return (unsigned short)(r >> 16);
}
static __device__ __forceinline__ bf16x8 ld_bf16x8(const void* p) {
    int4 v = *reinterpret_cast<const int4*>(p);
    return __builtin_bit_cast(bf16x8, v);
}
static __device__ __forceinline__ void gl_lds16(const void* g, void* l) {
    __builtin_amdgcn_global_load_lds((as1_t)(size_t)g, (as3_t)l, 16, 0, 0);
}

// ---------------- f32 -> bf16 convert (weights) ----------------
__global__ __launch_bounds__(256) void k_cvt(const float* __restrict__ src,
                                             unsigned short* __restrict__ dst, int n4) {
    int i = blockIdx.x * 256 + threadIdx.x;
    if (i < n4) {
        float4 v = reinterpret_cast<const float4*>(src)[i];
        uint2 o;
        o.x = (unsigned)f2bf(v.x) | ((unsigned)f2bf(v.y) << 16);
        o.y = (unsigned)f2bf(v.z) | ((unsigned)f2bf(v.w) << 16);
        reinterpret_cast<uint2*>(dst)[i] = o;
    }
}

// ---------------- LayerNorm(x) -> xn bf16 ; raw x,prefix -> kvin bf16 ----------------
__global__ __launch_bounds__(256) void k_ln_cvt(
    const float* __restrict__ x, const float* __restrict__ prefix,
    const float* __restrict__ gamma,
    unsigned short* __restrict__ xn, unsigned short* __restrict__ kvin)
{
    __shared__ float red[8];
    const int bid = blockIdx.x;
    const int t = threadIdx.x;
    const int w = t >> 6, lane = t & 63;
    if (bid < B_ * N_) {
        const int b = bid >> 10, n = bid & 1023;
        float4 v = reinterpret_cast<const float4*>(x + (size_t)bid * DIM)[t];
        uint2 raw;
        raw.x = (unsigned)f2bf(v.x) | ((unsigned)f2bf(v.y) << 16);
        raw.y = (unsigned)f2bf(v.z) | ((unsigned)f2bf(v.w) << 16);
        reinterpret_cast<uint2*>(kvin + ((size_t)b * J_ + P_ + n) * DIM)[t] = raw;
        float s = v.x + v.y + v.z + v.w;
        float ss = v.x*v.x + v.y*v.y + v.z*v.z + v.w*v.w;
        #pragma unroll
        for (int off = 32; off > 0; off >>= 1) {
            s  += __shfl_xor(s, off, 64);
            ss += __shfl_xor(ss, off, 64);
        }
        if (lane == 0) { red[w*2] = s; red[w*2+1] = ss; }
        __syncthreads();
        s  = red[0] + red[2] + red[4] + red[6];
        ss = red[1] + red[3] + red[5] + red[7];
        float mu = s * (1.0f / DIM);
        float var = ss * (1.0f / DIM) - mu * mu;
        float rs = rsqrtf(var + 1e-5f);
        float4 g = reinterpret_cast<const float4*>(gamma)[t];
        float o0 = (v.x - mu) * rs * g.x;
        float o1 = (v.y - mu) * rs * g.y;
        float o2 = (v.z - mu) * rs * g.z;
        float o3 = (v.w - mu) * rs * g.w;
        uint2 on;
        on.x = (unsigned)f2bf(o0) | ((unsigned)f2bf(o1) << 16);
        on.y = (unsigned)f2bf(o2) | ((unsigned)f2bf(o3) << 16);
        reinterpret_cast<uint2*>(xn + (size_t)bid * DIM)[t] = on;
    } else {
        const int r = bid - B_ * N_;
        const int b = r >> 10, jr = r & 1023;
        float4 v = reinterpret_cast<const float4*>(prefix + (size_t)r * DIM)[t];
        uint2 raw;
        raw.x = (unsigned)f2bf(v.x) | ((unsigned)f2bf(v.y) << 16);
        raw.y = (unsigned)f2bf(v.z) | ((unsigned)f2bf(v.w) << 16);
        reinterpret_cast<uint2*>(kvin + ((size_t)b * J_ + jr) * DIM)[t] = raw;
    }
}

// ---------------- GEMM: C[M,N] f32 = A[M,K]bf16 * B[N,K]bf16^T ----------------
// tile 128x128, BK=64, 4 waves each 64x64, 16x16x32 MFMA, swizzled LDS.
__global__ __launch_bounds__(256) void k_gemm_bt(
    const unsigned short* __restrict__ A, const unsigned short* __restrict__ Bm,
    float* __restrict__ C, int K, int ldc)
{
    __shared__ __align__(16) unsigned short As[128 * 64];
    __shared__ __align__(16) unsigned short Bs[128 * 64];
    const int tid = threadIdx.x;
    const int w = tid >> 6, lane = tid & 63;
    const int lg = lane >> 4, ll = lane & 15;
    const int m0 = blockIdx.y * 128, n0 = blockIdx.x * 128;
    const int wm = w >> 1, wn = w & 1;
    f32x4 acc[4][4];
    #pragma unroll
    for (int i = 0; i < 4; ++i)
        #pragma unroll
        for (int j = 0; j < 4; ++j)
            acc[i][j] = f32x4{0.f, 0.f, 0.f, 0.f};

    for (int k0 = 0; k0 < K; k0 += 64) {
        const unsigned short* Ab = A + (size_t)m0 * K + k0;
        const unsigned short* Bb = Bm + (size_t)n0 * K + k0;
        #pragma unroll
        for (int s = 0; s < 4; ++s) {
            int chunk = s * 256 + w * 64 + lane;
            int row = chunk >> 3, c = chunk & 7;
            int sc = (c ^ (row & 7)) * 8;
            gl_lds16(Ab + (size_t)row * K + sc, &As[(s * 256 + w * 64) * 8]);
            gl_lds16(Bb + (size_t)row * K + sc, &Bs[(s * 256 + w * 64) * 8]);
        }
        __syncthreads();
        bf16x8 af[4][2], bfr[4][2];
        #pragma unroll
        for (int ms = 0; ms < 4; ++ms) {
            #pragma unroll
            for (int ks = 0; ks < 2; ++ks) {
                int r = wm * 64 + ms * 16 + ll;
                int gc = ks * 4 + lg;
                af[ms][ks] = ld_bf16x8((const char*)As + r * 128 + ((gc ^ (r & 7)) << 4));
            }
        }
        #pragma unroll
        for (int ns = 0; ns < 4; ++ns) {
            #pragma unroll
            for (int ks = 0; ks < 2; ++ks) {
                int r = wn * 64 + ns * 16 + ll;
                int gc = ks * 4 + lg;
                bfr[ns][ks] = ld_bf16x8((const char*)Bs + r * 128 + ((gc ^ (r & 7)) << 4));
            }
        }
        #pragma unroll
        for (int ks = 0; ks < 2; ++ks)
            #pragma unroll
            for (int ms = 0; ms < 4; ++ms)
                #pragma unroll
                for (int ns = 0; ns < 4; ++ns)
                    acc[ms][ns] = __builtin_amdgcn_mfma_f32_16x16x32_bf16(
                        af[ms][ks], bfr[ns][ks], acc[ms][ns], 0, 0, 0);
        __syncthreads();
    }
    #pragma unroll
    for (int ms = 0; ms < 4; ++ms) {
        #pragma unroll
        for (int ns = 0; ns < 4; ++ns) {
            int col = n0 + wn * 64 + ns * 16 + ll;
            int rbase = m0 + wm * 64 + ms * 16 + lg * 4;
            #pragma unroll
            for (int rr = 0; rr < 4; ++rr)
                C[(size_t)(rbase + rr) * ldc + col] = acc[ms][ns][rr];
        }
    }
}

// ---------------- Q epilogue: l2norm over head dim + scale -> bf16 [B,H,N,DH] ----------------
__global__ __launch_bounds__(256) void k_q_epi(const float* __restrict__ Qg,
    const float* __restrict__ q_scale, unsigned short* __restrict__ QA)
{
    int gw = blockIdx.x * 4 + (threadIdx.x >> 6);
    int lane = threadIdx.x & 63;
    int m = gw >> 4, h = gw & 15;
    int b = m >> 10, n = m & 1023;
    float v = Qg[(size_t)m * DIM + h * DH + lane];
    float ss = v * v;
    #pragma unroll
    for (int off = 32; off > 0; off >>= 1) ss += __shfl_xor(ss, off, 64);
    float inv = 1.0f / fmaxf(sqrtf(ss), 1e-12f);
    QA[(((size_t)(b * 16 + h)) * N_ + n) * DH + lane] = f2bf(v * inv * q_scale[lane]);
}

// ---------------- KV epilogue: K l2norm -> bf16 [B,J,DH]; V -> Vt bf16 [B,DH,J] ----------------
__global__ __launch_bounds__(256) void k_kv_epi(const float* __restrict__ KVg,
    const float* __restrict__ k_scale, unsigned short* __restrict__ Kb,
    unsigned short* __restrict__ Vt)
{
    __shared__ __align__(16) unsigned short Vs[64 * 64];
    const int blk = blockIdx.x;
    const int t = threadIdx.x;
    const int w = t >> 6, lane = t & 63;
    const int rowbase = blk * 64;
    const int b = rowbase >> 11;
    const int jloc = rowbase & 2047;
    float kscale = k_scale[lane];
    #pragma unroll
    for (int it = 0; it < 16; ++it) {
        int row = rowbase + w * 16 + it;
        float v = KVg[(size_t)row * 128 + lane];
        float ss = v * v;
        #pragma unroll
        for (int off = 32; off > 0; off >>= 1) ss += __shfl_xor(ss, off, 64);
        float inv = 1.0f / fmaxf(sqrtf(ss), 1e-12f);
        Kb[(size_t)row * DH + lane] = f2bf(v * inv * kscale);
    }
    // transpose V through LDS
    const int r = t >> 2;
    const int cb = (t & 3) * 16;
    #pragma unroll
    for (int c4 = 0; c4 < 4; ++c4) {
        float4 v = *reinterpret_cast<const float4*>(&KVg[(size_t)(rowbase + r) * 128 + 64 + cb + c4 * 4]);
        Vs[(cb + c4 * 4 + 0) * 64 + r] = f2bf(v.x);
        Vs[(cb + c4 * 4 + 1) * 64 + r] = f2bf(v.y);
        Vs[(cb + c4 * 4 + 2) * 64 + r] = f2bf(v.z);
        Vs[(cb + c4 * 4 + 3) * 64 + r] = f2bf(v.w);
    }
    __syncthreads();
    const int d = t >> 2;
    const int jl = (t & 3) * 16;
    const int4* vsp = reinterpret_cast<const int4*>(&Vs[d * 64 + jl]);
    int4* dst = reinterpret_cast<int4*>(&Vt[((size_t)(b * 64 + d)) * J_ + jloc + jl]);
    dst[0] = vsp[0];
    dst[1] = vsp[1];
}

// ---------------- fused masked attention, flash-style ----------------
// grid: b*256 + h*16 + qt ; block 256 (4 waves), each wave 16 query rows.
__global__ __launch_bounds__(256) void k_attn(
    const unsigned short* __restrict__ QA, const unsigned short* __restrict__ Kb,
    const unsigned short* __restrict__ Vt, const float* __restrict__ bias,
    unsigned short* __restrict__ AO)
{
    __shared__ __align__(16) unsigned short Ks[64 * 64];
    __shared__ __align__(16) unsigned short Vsh[64 * 64];
    __shared__ __align__(16) unsigned short Ps[4][16 * 64];
    const int t = threadIdx.x, w = t >> 6, lane = t & 63;
    const int lg = lane >> 4, ll = lane & 15;
    const int qt = blockIdx.x & 15;
    const int h = (blockIdx.x >> 4) & 15;
    const int b = blockIdx.x >> 8;
    const int qbase = qt * 64;
    const float NEG_INF = -__builtin_inff();

    bf16x8 qf[2];
    {
        const unsigned short* qrow = QA + (((size_t)(b * 16 + h)) * N_ + qbase + w * 16 + ll) * DH;
        qf[0] = ld_bf16x8(qrow + lg * 8);
        qf[1] = ld_bf16x8(qrow + 32 + lg * 8);
    }
    float mrow[4], lrow[4];
    f32x4 o[4];
    #pragma unroll
    for (int rr = 0; rr < 4; ++rr) { mrow[rr] = -1e30f; lrow[rr] = 0.f; }
    #pragma unroll
    for (int ds = 0; ds < 4; ++ds) o[ds] = f32x4{0.f, 0.f, 0.f, 0.f};

    const int npre = (qt > 0) ? 2 : 1;
    const int nt = npre + qt + 1;
    for (int idx = 0; idx < nt; ++idx) {
        const bool is_pre = idx < npre;
        const int tpre = (qt > 0) ? (qt - 1 + idx) : 0;
        const int kt = idx - npre;
        const int kvrow = is_pre ? tpre * 64 : P_ + kt * 64;
        {
            const unsigned short* Kbase = Kb + ((size_t)b * J_ + kvrow) * DH;
            const unsigned short* Vbase = Vt + ((size_t)b * 64) * J_ + kvrow;
            #pragma unroll
            for (int s = 0; s < 2; ++s) {
                int chunk = s * 256 + w * 64 + lane;
                int row = chunk >> 3, c = chunk & 7;
                int sc = (c ^ (row & 7)) * 8;
                gl_lds16(Kbase + (size_t)row * DH + sc, &Ks[(s * 256 + w * 64) * 8]);
                gl_lds16(Vbase + (size_t)row * J_ + sc, &Vsh[(s * 256 + w * 64) * 8]);
            }
        }
        __syncthreads();
        f32x4 sv[4];
        #pragma unroll
        for (int ns = 0; ns < 4; ++ns) {
            f32x4 s = f32x4{0.f, 0.f, 0.f, 0.f};
            #pragma unroll
            for (int ks = 0; ks < 2; ++ks) {
                int r = ns * 16 + ll;
                int gc = ks * 4 + lg;
                bf16x8 bfr = ld_bf16x8((const char*)Ks + r * 128 + ((gc ^ (r & 7)) << 4));
                s = __builtin_amdgcn_mfma_f32_16x16x32_bf16(qf[ks], bfr, s, 0, 0, 0);
            }
            sv[ns] = s;
        }
        #pragma unroll
        for (int ns = 0; ns < 4; ++ns) {
            #pragma unroll
            for (int rr = 0; rr < 4; ++rr) {
                int i = qbase + w * 16 + lg * 4 + rr;
                int key = ns * 16 + ll;
                float val = sv[ns][rr] * SCALE_;
                if (is_pre) {
                    int cc = kvrow + key;
                    bool ok = (i >= cc) && (i - cc < WIND);
                    val = ok ? val : NEG_INF;
                } else {
                    int j2 = kt * 64 + key;
                    val += bias[((size_t)h * N_ + i) * N_ + j2];
                    if (j2 > i) val = NEG_INF;
                }
                sv[ns][rr] = val;
            }
        }
        float al[4];
        #pragma unroll
        for (int rr = 0; rr < 4; ++rr) {
            float mx = fmaxf(fmaxf(sv[0][rr], sv[1][rr]), fmaxf(sv[2][rr], sv[3][rr]));
            #pragma unroll
            for (int off = 1; off < 16; off <<= 1) mx = fmaxf(mx, __shfl_xor(mx, off, 64));
            float mn = fmaxf(mrow[rr], mx);
            al[rr] = __expf(mrow[rr] - mn);
            mrow[rr] = mn;
        }
        float rsum[4];
        #pragma unroll
        for (int rr = 0; rr < 4; ++rr) rsum[rr] = 0.f;
        #pragma unroll
        for (int ns = 0; ns < 4; ++ns) {
            #pragma unroll
            for (int rr = 0; rr < 4; ++rr) {
                float p = __expf(sv[ns][rr] - mrow[rr]);
                sv[ns][rr] = p;
                rsum[rr] += p;
            }
        }
        #pragma unroll
        for (int rr = 0; rr < 4; ++rr) {
            float rsv = rsum[rr];
            #pragma unroll
            for (int off = 1; off < 16; off <<= 1) rsv += __shfl_xor(rsv, off, 64);
            lrow[rr] = lrow[rr] * al[rr] + rsv;
        }
        #pragma unroll
        for (int ds = 0; ds < 4; ++ds)
            #pragma unroll
            for (int rr = 0; rr < 4; ++rr)
                o[ds][rr] *= al[rr];
        char* pbase = (char*)&Ps[w][0];
        #pragma unroll
        for (int ns = 0; ns < 4; ++ns) {
            #pragma unroll
            for (int rr = 0; rr < 4; ++rr) {
                int ql = lg * 4 + rr;
                int jc = ns * 16 + ll;
                int byteoff = ql * 128 + (((jc >> 3) ^ (ql & 7)) << 4) + (jc & 7) * 2;
                *reinterpret_cast<unsigned short*>(pbase + byteoff) = f2bf(sv[ns][rr]);
            }
        }
        __syncthreads();
        bf16x8 pa[2];
        #pragma unroll
        for (int ks = 0; ks < 2; ++ks) {
            int gc = ks * 4 + lg;
            pa[ks] = ld_bf16x8(pbase + ll * 128 + ((gc ^ (ll & 7)) << 4));
        }
        #pragma unroll
        for (int ds = 0; ds < 4; ++ds) {
            #pragma unroll
            for (int ks = 0; ks < 2; ++ks) {
                int rd = ds * 16 + ll;
                int gc = ks * 4 + lg;
                bf16x8 bv = ld_bf16x8((const char*)Vsh + rd * 128 + ((gc ^ (rd & 7)) << 4));
                o[ds] = __builtin_amdgcn_mfma_f32_16x16x32_bf16(pa[ks], bv, o[ds], 0, 0, 0);
            }
        }
        __syncthreads();
    }
    #pragma unroll
    for (int rr = 0; rr < 4; ++rr) {
        float inv = 1.0f / lrow[rr];
        int i = qbase + w * 16 + lg * 4 + rr;
        unsigned short* orow = AO + ((size_t)b * N_ + i) * DIM + h * DH;
        #pragma unroll
        for (int ds = 0; ds < 4; ++ds)
            orow[ds * 16 + ll] = f2bf(o[ds][rr] * inv);
    }
}

extern "C" void kernel_launch(void* const* d_in, const int* in_sizes, int n_in,
                              void* d_out, int out_size, void* d_ws, size_t ws_size,
                              hipStream_t stream)
{
    const float* x       = (const float*)d_in[0];
    const float* prefix  = (const float*)d_in[1];
    const float* bias    = (const float*)d_in[2];
    const float* gamma   = (const float*)d_in[3];
    const float* Wq      = (const float*)d_in[4];
    const float* Wkv     = (const float*)d_in[5];
    const float* q_scale = (const float*)d_in[6];
    const float* k_scale = (const float*)d_in[7];
    const float* Wo      = (const float*)d_in[8];
    float* out = (float*)d_out;

    char* ws = (char*)d_ws;
    unsigned short* xn   = (unsigned short*)(ws);              // 8 MB  [4096,1024] bf16
    unsigned short* kvin = (unsigned short*)(ws + 8388608);    // 16 MB [4,2048,1024] bf16
    unsigned short* wqb  = (unsigned short*)(ws + 25165824);   // 2 MB
    unsigned short* wkvb = (unsigned short*)(ws + 27262976);   // 256 KB
    unsigned short* wob  = (unsigned short*)(ws + 27525120);   // 2 MB
    float* qg            = (float*)(ws + 29622272);            // 16 MB [4096,1024] f32
    float* kvg           = (float*)(ws + 46399488);            // 4 MB  [8192,128] f32
    unsigned short* qa   = (unsigned short*)(ws + 50593792);   // 8 MB  [B,H,N,DH] bf16
    unsigned short* kb   = (unsigned short*)(ws + 58982400);   // 1 MB  [B,J,DH] bf16
    unsigned short* vt   = (unsigned short*)(ws + 60030976);   // 1 MB  [B,DH,J] bf16
    unsigned short* ao   = (unsigned short*)(ws + 61079552);   // 8 MB  [4096,1024] bf16

    k_cvt<<<1024, 256, 0, stream>>>(Wq, wqb, 262144);
    k_cvt<<<128, 256, 0, stream>>>(Wkv, wkvb, 32768);
    k_cvt<<<1024, 256, 0, stream>>>(Wo, wob, 262144);
    k_ln_cvt<<<8192, 256, 0, stream>>>(x, prefix, gamma, xn, kvin);
    k_gemm_bt<<<dim3(8, 32), 256, 0, stream>>>(xn, wqb, qg, 1024, 1024);
    k_gemm_bt<<<dim3(1, 64), 256, 0, stream>>>(kvin, wkvb, kvg, 1024, 128);
    k_q_epi<<<16384, 256, 0, stream>>>(qg, q_scale, qa);
    k_kv_epi<<<128, 256, 0, stream>>>(kvg, k_scale, kb, vt);
    k_attn<<<1024, 256, 0, stream>>>(qa, kb, vt, bias, ao);
    k_gemm_bt<<<dim3(8, 32), 256, 0, stream>>>(ao, wob, out, 1024, 1024);
}